// Round 20
// baseline (42.520 us; speedup 1.0000x reference)
//
#include <hip/hip_runtime.h>
#include <hip/hip_bf16.h>
#include <stdint.h>

#define DD 4
#define NVERT 5
#define NPTS 1024
#define BATCH 4
#define M0 5120           /* NPTS*NVERT */
#define CIN 64
#define COUT 64
#define NF 31
#define KTOT 1984         /* NF*CIN */
#define CAP 16384
#define CAPMASK (CAP-1)
#define SENTV 1073741824  /* 2^30, > any valid code (<128^4) */
#define ZROW (BATCH*M0)   /* zero row index in table_bf */

using bf16x8 = __attribute__((ext_vector_type(8))) short;
using f32x4  = __attribute__((ext_vector_type(4))) float;

__device__ __forceinline__ unsigned short f2bf(float x){
  unsigned int u = __float_as_uint(x);
  u = (u + 0x7FFFu + ((u >> 16) & 1u)) >> 16;
  return (unsigned short)u;
}

__device__ __forceinline__ uint32_t hslot(int code){
  return (((uint32_t)code * 2654435761u) >> 18) & CAPMASK;
}

// ---- shared simplex math ----
__device__ __forceinline__ void pv_math(const float* feat, int g, int* code_out, float* bary_out){
  int p = g / NVERT, kk = g % NVERT;
  int b = p >> 10, n = p & 1023;
  const float* fb = feat + (size_t)b * DD * NPTS + n;
  float f0 = fb[0], f1 = fb[NPTS], f2 = fb[2 * NPTS], f3 = fb[3 * NPTS];

  float elev[5];
  elev[0] =  f0 * 2.886751345948129f  + f1 * 1.6666666666666667f + f2 * 1.1785113019775793f + f3 * 0.9128709291752769f;
  elev[1] = -f0 * 2.886751345948129f  + f1 * 1.6666666666666667f + f2 * 1.1785113019775793f + f3 * 0.9128709291752769f;
  elev[2] =  f1 * -3.3333333333333335f + f2 * 1.1785113019775793f + f3 * 0.9128709291752769f;
  elev[3] =  f2 * -3.535533905932738f  + f3 * 0.9128709291752769f;
  elev[4] =  f3 * -3.6514837167011076f;

  int gi[5]; float diff[5]; int sum = 0;
  #pragma unroll
  for (int i = 0; i < 5; i++){
    float gg = rintf(elev[i] * 0.2f) * 5.0f;
    gi[i] = (int)rintf(gg);
    sum += gi[i];
    diff[i] = elev[i] - gg;
  }
  int s = sum / 5;

  int rank[5];
  #pragma unroll
  for (int i = 0; i < 5; i++){
    int r = 0;
    #pragma unroll
    for (int j = 0; j < 5; j++)
      r += (diff[j] > diff[i]) || (diff[j] == diff[i] && j < i);
    rank[i] = r + s;
  }
  #pragma unroll
  for (int i = 0; i < 5; i++){
    if (rank[i] < 0)      { rank[i] += NVERT; gi[i] += NVERT; }
    else if (rank[i] > DD){ rank[i] -= NVERT; gi[i] -= NVERT; }
  }

  float bary[6] = {0.f,0.f,0.f,0.f,0.f,0.f};
  #pragma unroll
  for (int i = 0; i < 5; i++){
    float tt = (elev[i] - (float)gi[i]) * 0.2f;
    bary[DD - rank[i]]    += tt;
    bary[NVERT - rank[i]] += 1.0f - tt;
  }
  bary[0] += 1.0f + bary[5];

  float bk = bary[0];
  #pragma unroll
  for (int i = 1; i < 5; i++) if (i == kk) bk = bary[i];

  int code = 0;
  #pragma unroll
  for (int j = 0; j < DD; j++){
    int add = (rank[j] >= NVERT - kk) ? (kk - NVERT) : kk;
    int key = gi[j] + add;
    key = min(63, max(-64, key));
    code += (key + 64) << (7 * j);
  }
  *code_out = code;
  *bary_out = bk;
}

// ============ A: init + bpf + dat_t + pmath (disjoint block ranges) =======
__global__ void k_a(const float* __restrict__ wk, const float* __restrict__ data,
                    const float* __restrict__ feat,
                    int* __restrict__ hc, int* __restrict__ hu, int* __restrict__ uc,
                    float4* __restrict__ table4, float4* __restrict__ outlat4,
                    unsigned short* __restrict__ bpf, float* __restrict__ dat_t,
                    int* __restrict__ codes_pv, float* __restrict__ bary_pv){
  int bid = blockIdx.x, tid = threadIdx.x;
  if (bid < 64){
    __shared__ float tile[64][65];
    int b = bid >> 4, n0 = (bid & 15) * 64;
    int nl = tid & 63;
    #pragma unroll
    for (int i = 0; i < 16; i++){
      int c = (tid >> 6) * 16 + i;
      tile[c][nl] = data[(((size_t)b * 64 + c) << 10) + n0 + nl];
    }
    __syncthreads();
    #pragma unroll
    for (int i = 0; i < 16; i++){
      int nn = (tid >> 6) * 16 + i;
      dat_t[(((size_t)b << 10) + n0 + nn) * 64 + (tid & 63)] = tile[tid & 63][nn];
    }
  } else if (bid < 144){
    int g = (bid - 64) * 256 + tid;
    int code; float bk;
    pv_math(feat, g, &code, &bk);
    codes_pv[g] = code;
    bary_pv[g]  = bk;
  } else if (bid < 640){
    // weights -> fragment-ordered bpf
    int e = (bid - 144) * 256 + tid;
    int frag = e >> 9, l = (e >> 3) & 63, j = e & 7;
    int f = frag >> 3, h = (frag >> 2) & 1, g = frag & 3;
    int col = g * 16 + (l & 15);
    int c = h * 32 + ((l >> 4) << 3) + j;
    bpf[e] = f2bf(wk[(col * CIN + c) * NF + f]);
  } else {
    int g = (bid - 640) * 256 + tid;
    int stride = 384 * 256;
    for (int i = g; i < BATCH * CAP; i += stride){ hc[i] = SENTV; hu[i] = -1; }
    if (g < BATCH) uc[g] = 0;
    float4 z = {0.f,0.f,0.f,0.f};
    for (int i = g; i < BATCH * M0 * CIN / 4; i += stride) table4[i] = z;
    for (int i = g; i < BATCH * M0 * COUT / 4; i += stride) outlat4[i] = z;
  }
}

// ============ insert: LDS dedupe + global CAS + wave-aggregated uid =======
__global__ void k_insert(const int* __restrict__ codes_pv,
                         int* __restrict__ hash_code, int* __restrict__ hash_uid,
                         int* __restrict__ ucount, int* __restrict__ ukeys){
  __shared__ int lhash[512];
  int tid = threadIdx.x;
  lhash[tid] = SENTV; lhash[tid + 256] = SENTV;
  __syncthreads();

  int g = blockIdx.x * 256 + tid;
  int b = g / M0;
  int code = codes_pv[g];

  uint32_t lh = (((uint32_t)code * 2654435761u) >> 21) & 511;
  bool rep = false;
  while (true){
    int prev = atomicCAS(&lhash[lh], SENTV, code);
    if (prev == SENTV){ rep = true; break; }
    if (prev == code) break;
    lh = (lh + 1) & 511;
  }

  int myslot = -1;
  if (rep){
    int* hc = hash_code + b * CAP;
    uint32_t h = hslot(code);
    while (true){
      int prev = atomicCAS(&hc[h], SENTV, code);
      if (prev == SENTV){ myslot = (int)h; break; }
      if (prev == code) break;
      h = (h + 1) & CAPMASK;
    }
  }

  unsigned long long mask = __ballot(myslot >= 0);
  if (mask){
    int lane = tid & 63;
    int cnt = __popcll(mask);
    int leader = __ffsll((unsigned long long)mask) - 1;
    int base = 0;
    if (lane == leader) base = atomicAdd(&ucount[b], cnt);
    base = __shfl(base, leader);
    if (myslot >= 0){
      int rank = __popcll(mask & ((1ull << lane) - 1ull));
      int uid = base + rank;
      hash_uid[b * CAP + myslot] = uid;
      int* uk = ukeys + ((size_t)(b * M0 + uid)) * DD;
      #pragma unroll
      for (int j = 0; j < DD; j++) uk[j] = ((code >> (7 * j)) & 127) - 64;
    }
  }
}

// ============ splat only: one wave per point, coalesced ===================
__global__ void k_sn(const float* __restrict__ dat_t, const int* __restrict__ codes_pv,
                     const float* __restrict__ bary_pv, const int* __restrict__ hash_code,
                     const int* __restrict__ hash_uid,
                     int* __restrict__ idx_pv, float* __restrict__ table){
  __shared__ int   us[4][8];
  __shared__ float wbs[4][8];
  int tid = threadIdx.x;
  int w = tid >> 6, lane = tid & 63;
  int p = blockIdx.x * 4 + w;
  int b = p >> 10;
  float v = dat_t[((size_t)p << 6) + lane];
  if (lane < NVERT){
    int code = codes_pv[p * NVERT + lane];
    const int* hc = hash_code + b * CAP;
    uint32_t h = hslot(code);
    while (hc[h] != code) h = (h + 1) & CAPMASK;
    int uid = hash_uid[b * CAP + h];
    us[w][lane]  = uid;
    wbs[w][lane] = bary_pv[p * NVERT + lane];
    idx_pv[p * NVERT + lane] = uid;
  }
  __syncthreads();
  int rot = p % NVERT;
  #pragma unroll
  for (int kq = 0; kq < NVERT; kq++){
    int kk = kq + rot; if (kk >= NVERT) kk -= NVERT;
    atomicAdd(&table[(((size_t)(b * M0 + us[w][kk])) << 6) + lane], v * wbs[w][kk]);
  }
}

// ============ table fp32 -> bf16 (+ zero row), skip unused rows ===========
__global__ void k_tobf(const float* __restrict__ table, const int* __restrict__ ucount,
                       unsigned short* __restrict__ table_bf){
  int g = blockIdx.x * blockDim.x + threadIdx.x;
  if (g < 8){
    bf16x8 z = {0,0,0,0,0,0,0,0};
    *(bf16x8*)(table_bf + ((size_t)ZROW << 6) + g * 8) = z;
  }
  int row = g >> 3;
  int b = row / M0;
  if (row - b * M0 >= ucount[b]) return;   // unused rows never read by conv
  size_t base = (size_t)g * 8;
  const float4* s4 = (const float4*)(table + base);
  float4 x = s4[0], y = s4[1];
  bf16x8 v;
  v[0] = (short)f2bf(x.x); v[1] = (short)f2bf(x.y);
  v[2] = (short)f2bf(x.z); v[3] = (short)f2bf(x.w);
  v[4] = (short)f2bf(y.x); v[5] = (short)f2bf(y.y);
  v[6] = (short)f2bf(y.z); v[7] = (short)f2bf(y.w);
  *(bf16x8*)(table_bf + base) = v;
}

// ============ conv: fused neighbor lookup + 8-way f-split MFMA ============
__launch_bounds__(512, 4)
__global__ void k_conv(const int* __restrict__ ucount, const int* __restrict__ ukeys,
                       const int* __restrict__ hash_code, const int* __restrict__ hash_uid,
                       const unsigned short* __restrict__ table_bf,
                       const unsigned short* __restrict__ bpf,
                       float* __restrict__ out_lat){
  __shared__ int uk_s[64][4];
  __shared__ int gidx_s[64 * 17];    // [row][fl], fl in 0..15 (local f), pad 17
  __shared__ float red[7][64][17];   // per-rg chunk: [wave-1][lane][16 vals + pad]

  int blk = blockIdx.x;
  int b    = blk / 160;          // 160 = 80 tiles * 2 halves
  int r    = blk % 160;
  int m0   = (r >> 1) * 64;
  int half = r & 1;
  int ucnt = ucount[b];
  if (m0 >= ucnt) return;

  int tid = threadIdx.x;
  // stage ukeys for the 64 rows (coalesced; stale rows guarded later)
  if (tid < 256){
    int row = tid >> 2, j = tid & 3;
    uk_s[row][j] = ukeys[((size_t)(b * M0 + m0 + row)) * DD + j];
  }
  __syncthreads();

  // fused neighbor lookups: 64 rows x 16 local f, 2 per thread
  {
    const int* hc = hash_code + b * CAP;
    const int* hu = hash_uid  + b * CAP;
    #pragma unroll
    for (int it = 0; it < 2; it++){
      int li = tid + it * 512;
      int row = li & 63, fl = li >> 6;
      int f = half * 16 + fl;
      int m = m0 + row;
      int g = ZROW;
      if (f < NF && m < ucnt){
        int pc = __popc(f);
        int code = 0;
        #pragma unroll
        for (int j = 0; j < DD; j++){
          int key = uk_s[row][j] + 5 * ((f >> j) & 1) - pc;
          key = min(63, max(-64, key));
          code += (key + 64) << (7 * j);
        }
        uint32_t h = hslot(code);
        while (true){
          int v = hc[h];
          if (v == code){ g = b * M0 + hu[h]; break; }
          if (v == SENTV) break;
          h = (h + 1) & CAPMASK;
        }
      }
      gidx_s[row * 17 + fl] = g;
    }
  }
  __syncthreads();

  int lane = tid & 63, wave = tid >> 6;   // wave 0..7 owns 2 f-values
  int rl = lane & 15;
  int acol = (lane >> 4) * 8;
  const unsigned short* bf_lane = bpf + ((size_t)lane << 3);

  f32x4 acc[4][4];                         // [row-group][g], 64 VGPRs
  #pragma unroll
  for (int rg = 0; rg < 4; rg++)
    #pragma unroll
    for (int g = 0; g < 4; g++)
      acc[rg][g] = (f32x4){0.f,0.f,0.f,0.f};

  int f0 = half * 16 + wave * 2;
  int f1 = f0 + 2; if (f1 > NF) f1 = NF;   // half-1 wave-7: single f=30

  for (int f = f0; f < f1; f++){
    int fl = f - half * 16;
    // A: all 4 row-groups x both 32-col halves (8 independent gathers)
    bf16x8 A0_0, A0_1, A1_0, A1_1, A2_0, A2_1, A3_0, A3_1;
    {
      const unsigned short* p0 = table_bf + (((size_t)gidx_s[(rl     ) * 17 + fl]) << 6) + acol;
      const unsigned short* p1 = table_bf + (((size_t)gidx_s[(rl + 16) * 17 + fl]) << 6) + acol;
      const unsigned short* p2 = table_bf + (((size_t)gidx_s[(rl + 32) * 17 + fl]) << 6) + acol;
      const unsigned short* p3 = table_bf + (((size_t)gidx_s[(rl + 48) * 17 + fl]) << 6) + acol;
      A0_0 = *(const bf16x8*)(p0); A0_1 = *(const bf16x8*)(p0 + 32);
      A1_0 = *(const bf16x8*)(p1); A1_1 = *(const bf16x8*)(p1 + 32);
      A2_0 = *(const bf16x8*)(p2); A2_1 = *(const bf16x8*)(p2 + 32);
      A3_0 = *(const bf16x8*)(p3); A3_1 = *(const bf16x8*)(p3 + 32);
    }
    int fr = f << 3;
    #pragma unroll
    for (int g = 0; g < 4; g++){
      bf16x8 B0 = *(const bf16x8*)(bf_lane + ((size_t)(fr + g)     << 9));  // h=0
      bf16x8 B1 = *(const bf16x8*)(bf_lane + ((size_t)(fr + 4 + g) << 9));  // h=1
      acc[0][g] = __builtin_amdgcn_mfma_f32_16x16x32_bf16(A0_0, B0, acc[0][g], 0, 0, 0);
      acc[0][g] = __builtin_amdgcn_mfma_f32_16x16x32_bf16(A0_1, B1, acc[0][g], 0, 0, 0);
      acc[1][g] = __builtin_amdgcn_mfma_f32_16x16x32_bf16(A1_0, B0, acc[1][g], 0, 0, 0);
      acc[1][g] = __builtin_amdgcn_mfma_f32_16x16x32_bf16(A1_1, B1, acc[1][g], 0, 0, 0);
      acc[2][g] = __builtin_amdgcn_mfma_f32_16x16x32_bf16(A2_0, B0, acc[2][g], 0, 0, 0);
      acc[2][g] = __builtin_amdgcn_mfma_f32_16x16x32_bf16(A2_1, B1, acc[2][g], 0, 0, 0);
      acc[3][g] = __builtin_amdgcn_mfma_f32_16x16x32_bf16(A3_0, B0, acc[3][g], 0, 0, 0);
      acc[3][g] = __builtin_amdgcn_mfma_f32_16x16x32_bf16(A3_1, B1, acc[3][g], 0, 0, 0);
    }
  }

  // chunked LDS reduction across the 8 waves (one row-group at a time)
  #pragma unroll
  for (int rg = 0; rg < 4; rg++){
    if (wave > 0){
      #pragma unroll
      for (int g = 0; g < 4; g++)
        #pragma unroll
        for (int q = 0; q < 4; q++)
          red[wave - 1][lane][g * 4 + q] = acc[rg][g][q];
    }
    __syncthreads();
    if (wave == 0){
      #pragma unroll
      for (int w = 0; w < 7; w++)
        #pragma unroll
        for (int g = 0; g < 4; g++)
          #pragma unroll
          for (int q = 0; q < 4; q++)
            acc[rg][g][q] += red[w][lane][g * 4 + q];
    }
    __syncthreads();
  }

  // wave0-only atomic epilogue: one add per output per half-block
  // C/D layout: col = lane&15, row = (lane>>4)*4 + q (m89-verified)
  if (wave == 0){
    int q4 = (lane >> 4) * 4, col = lane & 15;
    #pragma unroll
    for (int rg = 0; rg < 4; rg++){
      #pragma unroll
      for (int q = 0; q < 4; q++){
        int m = m0 + rg * 16 + q4 + q;
        float* orow = out_lat + (((size_t)(b * M0 + m)) << 6);
        #pragma unroll
        for (int g = 0; g < 4; g++){
          atomicAdd(&orow[g * 16 + col], acc[rg][g][q]);
        }
      }
    }
  }
}

// ============ slice + bias + transpose to [b][o][n], 16-row tiles =========
__global__ void k_slice(const float* __restrict__ bary_pv, const int* __restrict__ idx_pv,
                        const float* __restrict__ out_lat, const float* __restrict__ bias,
                        const float* __restrict__ bmul, float* __restrict__ out){
  __shared__ float tile[16][65];
  int b = blockIdx.x >> 6, n0 = (blockIdx.x & 63) * 16;
  int tid = threadIdx.x;
  int wave = tid >> 6, o = tid & 63;
  float bo = bias[o];
  #pragma unroll
  for (int i = 0; i < 4; i++){
    int n = wave * 4 + i;
    int p = (b << 10) + n0 + n;
    float acc = bo * bmul[n0 + n];
    int base = p * NVERT;
    #pragma unroll
    for (int kk = 0; kk < NVERT; kk++){
      int u = idx_pv[base + kk];
      acc += bary_pv[base + kk] * out_lat[(((size_t)(b * M0 + u)) << 6) + o];
    }
    tile[n][o] = acc;
  }
  __syncthreads();
  int nl = tid & 15;
  #pragma unroll
  for (int i = 0; i < 4; i++){
    int o2 = (tid >> 4) + i * 16;
    out[(((size_t)b * 64 + o2) << 10) + n0 + nl] = tile[nl][o2];
  }
}

extern "C" void kernel_launch(void* const* d_in, const int* in_sizes, int n_in,
                              void* d_out, int out_size, void* d_ws, size_t ws_size,
                              hipStream_t stream){
  const float* data = (const float*)d_in[0];
  const float* feat = (const float*)d_in[1];
  const float* wk   = (const float*)d_in[2];
  const float* bias = (const float*)d_in[3];
  const float* bmul = (const float*)d_in[4];
  float* out = (float*)d_out;

  char* ws = (char*)d_ws;
  size_t off = 0;
  auto alloc = [&](size_t bytes){
    void* p = ws + off;
    off = (off + bytes + 255) & ~(size_t)255;
    return p;
  };
  int*   codes_pv = (int*)  alloc((size_t)BATCH * M0 * 4);
  float* bary_pv  = (float*)alloc((size_t)BATCH * M0 * 4);
  int*   idx_pv   = (int*)  alloc((size_t)BATCH * M0 * 4);
  int*   hash_code= (int*)  alloc((size_t)BATCH * CAP * 4);
  int*   hash_uid = (int*)  alloc((size_t)BATCH * CAP * 4);
  int*   ucount   = (int*)  alloc(256);
  int*   ukeys    = (int*)  alloc((size_t)BATCH * M0 * DD * 4);
  float* table    = (float*)alloc((size_t)BATCH * M0 * CIN * 4);
  float* out_lat  = (float*)alloc((size_t)BATCH * M0 * COUT * 4);
  unsigned short* bpf      = (unsigned short*)alloc((size_t)COUT * KTOT * 2);
  unsigned short* table_bf = (unsigned short*)alloc(((size_t)BATCH * M0 + 8) * CIN * 2);
  float* dat_t    = (float*)alloc((size_t)BATCH * NPTS * CIN * 4);

  k_a     <<<1024, 256, 0, stream>>>(wk, data, feat, hash_code, hash_uid, ucount,
                                     (float4*)table, (float4*)out_lat, bpf, dat_t,
                                     codes_pv, bary_pv);
  k_insert<<<BATCH * M0 / 256, 256, 0, stream>>>(codes_pv, hash_code, hash_uid, ucount, ukeys);
  k_sn    <<<BATCH * NPTS / 4, 256, 0, stream>>>(dat_t, codes_pv, bary_pv,
                                                 hash_code, hash_uid, idx_pv, table);
  k_tobf  <<<BATCH * M0 * CIN / 8 / 256, 256, 0, stream>>>(table, ucount, table_bf);
  k_conv  <<<BATCH * 160, 512, 0, stream>>>(ucount, ukeys, hash_code, hash_uid,
                                            table_bf, bpf, out_lat);
  k_slice <<<BATCH * 64, 256, 0, stream>>>(bary_pv, idx_pv, out_lat, bias, bmul, out);
}

// Round 21
// 41.835 us; speedup vs baseline: 1.0164x; 1.0164x over previous
//
#include <hip/hip_runtime.h>
#include <hip/hip_bf16.h>
#include <stdint.h>

#define DD 4
#define NVERT 5
#define NPTS 1024
#define BATCH 4
#define M0 5120           /* NPTS*NVERT */
#define CIN 64
#define COUT 64
#define NF 31
#define KTOT 1984         /* NF*CIN */
#define CAP 16384
#define CAPMASK (CAP-1)
#define SENTV 1073741824  /* 2^30, > any valid code (<128^4) */
#define ZROW (BATCH*M0)   /* zero row index in table_bf */

using bf16x8 = __attribute__((ext_vector_type(8))) short;
using f32x4  = __attribute__((ext_vector_type(4))) float;

__device__ __forceinline__ unsigned short f2bf(float x){
  unsigned int u = __float_as_uint(x);
  u = (u + 0x7FFFu + ((u >> 16) & 1u)) >> 16;
  return (unsigned short)u;
}

__device__ __forceinline__ uint32_t hslot(int code){
  return (((uint32_t)code * 2654435761u) >> 18) & CAPMASK;
}

// ---- shared simplex math ----
__device__ __forceinline__ void pv_math(const float* feat, int g, int* code_out, float* bary_out){
  int p = g / NVERT, kk = g % NVERT;
  int b = p >> 10, n = p & 1023;
  const float* fb = feat + (size_t)b * DD * NPTS + n;
  float f0 = fb[0], f1 = fb[NPTS], f2 = fb[2 * NPTS], f3 = fb[3 * NPTS];

  float elev[5];
  elev[0] =  f0 * 2.886751345948129f  + f1 * 1.6666666666666667f + f2 * 1.1785113019775793f + f3 * 0.9128709291752769f;
  elev[1] = -f0 * 2.886751345948129f  + f1 * 1.6666666666666667f + f2 * 1.1785113019775793f + f3 * 0.9128709291752769f;
  elev[2] =  f1 * -3.3333333333333335f + f2 * 1.1785113019775793f + f3 * 0.9128709291752769f;
  elev[3] =  f2 * -3.535533905932738f  + f3 * 0.9128709291752769f;
  elev[4] =  f3 * -3.6514837167011076f;

  int gi[5]; float diff[5]; int sum = 0;
  #pragma unroll
  for (int i = 0; i < 5; i++){
    float gg = rintf(elev[i] * 0.2f) * 5.0f;
    gi[i] = (int)rintf(gg);
    sum += gi[i];
    diff[i] = elev[i] - gg;
  }
  int s = sum / 5;

  int rank[5];
  #pragma unroll
  for (int i = 0; i < 5; i++){
    int r = 0;
    #pragma unroll
    for (int j = 0; j < 5; j++)
      r += (diff[j] > diff[i]) || (diff[j] == diff[i] && j < i);
    rank[i] = r + s;
  }
  #pragma unroll
  for (int i = 0; i < 5; i++){
    if (rank[i] < 0)      { rank[i] += NVERT; gi[i] += NVERT; }
    else if (rank[i] > DD){ rank[i] -= NVERT; gi[i] -= NVERT; }
  }

  float bary[6] = {0.f,0.f,0.f,0.f,0.f,0.f};
  #pragma unroll
  for (int i = 0; i < 5; i++){
    float tt = (elev[i] - (float)gi[i]) * 0.2f;
    bary[DD - rank[i]]    += tt;
    bary[NVERT - rank[i]] += 1.0f - tt;
  }
  bary[0] += 1.0f + bary[5];

  float bk = bary[0];
  #pragma unroll
  for (int i = 1; i < 5; i++) if (i == kk) bk = bary[i];

  int code = 0;
  #pragma unroll
  for (int j = 0; j < DD; j++){
    int add = (rank[j] >= NVERT - kk) ? (kk - NVERT) : kk;
    int key = gi[j] + add;
    key = min(63, max(-64, key));
    code += (key + 64) << (7 * j);
  }
  *code_out = code;
  *bary_out = bk;
}

// ============ A: init + bpf + dat_t + pmath (disjoint block ranges) =======
__global__ void k_a(const float* __restrict__ wk, const float* __restrict__ data,
                    const float* __restrict__ feat,
                    int* __restrict__ hc, int* __restrict__ hu, int* __restrict__ uc,
                    float4* __restrict__ table4, float4* __restrict__ outlat4,
                    unsigned short* __restrict__ bpf, float* __restrict__ dat_t,
                    int* __restrict__ codes_pv, float* __restrict__ bary_pv){
  int bid = blockIdx.x, tid = threadIdx.x;
  if (bid < 64){
    __shared__ float tile[64][65];
    int b = bid >> 4, n0 = (bid & 15) * 64;
    int nl = tid & 63;
    #pragma unroll
    for (int i = 0; i < 16; i++){
      int c = (tid >> 6) * 16 + i;
      tile[c][nl] = data[(((size_t)b * 64 + c) << 10) + n0 + nl];
    }
    __syncthreads();
    #pragma unroll
    for (int i = 0; i < 16; i++){
      int nn = (tid >> 6) * 16 + i;
      dat_t[(((size_t)b << 10) + n0 + nn) * 64 + (tid & 63)] = tile[tid & 63][nn];
    }
  } else if (bid < 144){
    int g = (bid - 64) * 256 + tid;
    int code; float bk;
    pv_math(feat, g, &code, &bk);
    codes_pv[g] = code;
    bary_pv[g]  = bk;
  } else if (bid < 640){
    // weights -> fragment-ordered bpf
    int e = (bid - 144) * 256 + tid;
    int frag = e >> 9, l = (e >> 3) & 63, j = e & 7;
    int f = frag >> 3, h = (frag >> 2) & 1, g = frag & 3;
    int col = g * 16 + (l & 15);
    int c = h * 32 + ((l >> 4) << 3) + j;
    bpf[e] = f2bf(wk[(col * CIN + c) * NF + f]);
  } else {
    int g = (bid - 640) * 256 + tid;
    int stride = 384 * 256;
    for (int i = g; i < BATCH * CAP; i += stride){ hc[i] = SENTV; hu[i] = -1; }
    if (g < BATCH) uc[g] = 0;
    float4 z = {0.f,0.f,0.f,0.f};
    for (int i = g; i < BATCH * M0 * CIN / 4; i += stride) table4[i] = z;
    for (int i = g; i < BATCH * M0 * COUT / 4; i += stride) outlat4[i] = z;
  }
}

// ============ insert: LDS dedupe + global CAS + wave-aggregated uid =======
__global__ void k_insert(const int* __restrict__ codes_pv,
                         int* __restrict__ hash_code, int* __restrict__ hash_uid,
                         int* __restrict__ ucount, int* __restrict__ ukeys){
  __shared__ int lhash[512];
  int tid = threadIdx.x;
  lhash[tid] = SENTV; lhash[tid + 256] = SENTV;
  __syncthreads();

  int g = blockIdx.x * 256 + tid;
  int b = g / M0;
  int code = codes_pv[g];

  uint32_t lh = (((uint32_t)code * 2654435761u) >> 21) & 511;
  bool rep = false;
  while (true){
    int prev = atomicCAS(&lhash[lh], SENTV, code);
    if (prev == SENTV){ rep = true; break; }
    if (prev == code) break;
    lh = (lh + 1) & 511;
  }

  int myslot = -1;
  if (rep){
    int* hc = hash_code + b * CAP;
    uint32_t h = hslot(code);
    while (true){
      int prev = atomicCAS(&hc[h], SENTV, code);
      if (prev == SENTV){ myslot = (int)h; break; }
      if (prev == code) break;
      h = (h + 1) & CAPMASK;
    }
  }

  unsigned long long mask = __ballot(myslot >= 0);
  if (mask){
    int lane = tid & 63;
    int cnt = __popcll(mask);
    int leader = __ffsll((unsigned long long)mask) - 1;
    int base = 0;
    if (lane == leader) base = atomicAdd(&ucount[b], cnt);
    base = __shfl(base, leader);
    if (myslot >= 0){
      int rank = __popcll(mask & ((1ull << lane) - 1ull));
      int uid = base + rank;
      hash_uid[b * CAP + myslot] = uid;
      int* uk = ukeys + ((size_t)(b * M0 + uid)) * DD;
      #pragma unroll
      for (int j = 0; j < DD; j++) uk[j] = ((code >> (7 * j)) & 127) - 64;
    }
  }
}

// ============ fused: splat (blocks < 1024) + neighbor lookups (rest) ======
__global__ void k_sn(const float* __restrict__ dat_t, const int* __restrict__ codes_pv,
                     const float* __restrict__ bary_pv, const int* __restrict__ hash_code,
                     const int* __restrict__ hash_uid, const int* __restrict__ ucount,
                     const int* __restrict__ ukeys,
                     int* __restrict__ idx_pv, float* __restrict__ table,
                     int* __restrict__ nuid){
  int bid = blockIdx.x, tid = threadIdx.x;
  if (bid < BATCH * NPTS / 4){
    __shared__ int   us[4][8];
    __shared__ float wbs[4][8];
    int w = tid >> 6, lane = tid & 63;
    int p = bid * 4 + w;
    int b = p >> 10;
    float v = dat_t[((size_t)p << 6) + lane];
    if (lane < NVERT){
      int code = codes_pv[p * NVERT + lane];
      const int* hc = hash_code + b * CAP;
      uint32_t h = hslot(code);
      while (hc[h] != code) h = (h + 1) & CAPMASK;
      int uid = hash_uid[b * CAP + h];
      us[w][lane]  = uid;
      wbs[w][lane] = bary_pv[p * NVERT + lane];
      idx_pv[p * NVERT + lane] = uid;
    }
    __syncthreads();
    int rot = p % NVERT;
    #pragma unroll
    for (int kq = 0; kq < NVERT; kq++){
      int kk = kq + rot; if (kk >= NVERT) kk -= NVERT;
      atomicAdd(&table[(((size_t)(b * M0 + us[w][kk])) << 6) + lane], v * wbs[w][kk]);
    }
  } else {
    int e = (bid - BATCH * NPTS / 4) * 256 + tid;
    int f = e & 31;
    int idx = e >> 5;
    int b = idx / M0, m = idx - b * M0;
    int g = ZROW;
    if (f < NF && m < ucount[b]){
      const int* uk = ukeys + ((size_t)idx) * DD;
      int pc = __popc(f);
      int code = 0;
      #pragma unroll
      for (int j = 0; j < DD; j++){
        int key = uk[j] + 5 * ((f >> j) & 1) - pc;
        key = min(63, max(-64, key));
        code += (key + 64) << (7 * j);
      }
      const int* hc = hash_code + b * CAP;
      uint32_t h = hslot(code);
      while (true){
        int v = hc[h];
        if (v == code){ g = b * M0 + hash_uid[b * CAP + h]; break; }
        if (v == SENTV) break;
        h = (h + 1) & CAPMASK;
      }
    }
    nuid[e] = g;
  }
}

// ============ table fp32 -> bf16 (+ zero row), skip unused rows ===========
__global__ void k_tobf(const float* __restrict__ table, const int* __restrict__ ucount,
                       unsigned short* __restrict__ table_bf){
  int g = blockIdx.x * blockDim.x + threadIdx.x;
  if (g < 8){
    bf16x8 z = {0,0,0,0,0,0,0,0};
    *(bf16x8*)(table_bf + ((size_t)ZROW << 6) + g * 8) = z;
  }
  int row = g >> 3;
  int b = row / M0;
  if (row - b * M0 >= ucount[b]) return;   // unused rows never read by conv
  size_t base = (size_t)g * 8;
  const float4* s4 = (const float4*)(table + base);
  float4 x = s4[0], y = s4[1];
  bf16x8 v;
  v[0] = (short)f2bf(x.x); v[1] = (short)f2bf(x.y);
  v[2] = (short)f2bf(x.z); v[3] = (short)f2bf(x.w);
  v[4] = (short)f2bf(y.x); v[5] = (short)f2bf(y.y);
  v[6] = (short)f2bf(y.z); v[7] = (short)f2bf(y.w);
  *(bf16x8*)(table_bf + base) = v;
}

// ============ conv: 640 blocks, 8-way f-split (64 rows/wave), B dedup'd ===
__launch_bounds__(512, 4)
__global__ void k_conv(const int* __restrict__ ucount, const int* __restrict__ nuid,
                       const unsigned short* __restrict__ table_bf,
                       const unsigned short* __restrict__ bpf,
                       float* __restrict__ out_lat){
  __shared__ int gidx_s[64 * 33];
  __shared__ float red[7][64][17];   // per-rg chunk: [wave-1][lane][16 vals + pad]

  int blk = blockIdx.x;
  int b    = blk / 160;          // 160 = 80 tiles * 2 halves
  int r    = blk % 160;
  int m0   = (r >> 1) * 64;
  int half = r & 1;
  if (m0 >= ucount[b]) return;

  int tid = threadIdx.x;
  {
    int base = (b * M0 + m0) << 5;
    #pragma unroll
    for (int i = 0; i < 4; i++){
      int idx = tid + i * 512;
      gidx_s[(idx >> 5) * 33 + (idx & 31)] = nuid[base + idx];
    }
  }
  __syncthreads();

  int lane = tid & 63, wave = tid >> 6;   // wave 0..7 owns 2 f-values
  int rl = lane & 15;
  int acol = (lane >> 4) * 8;
  const unsigned short* bf_lane = bpf + ((size_t)lane << 3);

  f32x4 acc[4][4];                         // [row-group][g], 64 VGPRs
  #pragma unroll
  for (int rg = 0; rg < 4; rg++)
    #pragma unroll
    for (int g = 0; g < 4; g++)
      acc[rg][g] = (f32x4){0.f,0.f,0.f,0.f};

  int f0 = half * 16 + wave * 2;
  int f1 = f0 + 2; if (f1 > NF) f1 = NF;   // half-1 wave-7: single f=30

  for (int f = f0; f < f1; f++){
    // A: all 4 row-groups x both 32-col halves (8 independent gathers)
    bf16x8 A0_0, A0_1, A1_0, A1_1, A2_0, A2_1, A3_0, A3_1;
    {
      const unsigned short* p0 = table_bf + (((size_t)gidx_s[(rl     ) * 33 + f]) << 6) + acol;
      const unsigned short* p1 = table_bf + (((size_t)gidx_s[(rl + 16) * 33 + f]) << 6) + acol;
      const unsigned short* p2 = table_bf + (((size_t)gidx_s[(rl + 32) * 33 + f]) << 6) + acol;
      const unsigned short* p3 = table_bf + (((size_t)gidx_s[(rl + 48) * 33 + f]) << 6) + acol;
      A0_0 = *(const bf16x8*)(p0); A0_1 = *(const bf16x8*)(p0 + 32);
      A1_0 = *(const bf16x8*)(p1); A1_1 = *(const bf16x8*)(p1 + 32);
      A2_0 = *(const bf16x8*)(p2); A2_1 = *(const bf16x8*)(p2 + 32);
      A3_0 = *(const bf16x8*)(p3); A3_1 = *(const bf16x8*)(p3 + 32);
    }
    int fr = f << 3;
    #pragma unroll
    for (int g = 0; g < 4; g++){
      bf16x8 B0 = *(const bf16x8*)(bf_lane + ((size_t)(fr + g)     << 9));  // h=0
      bf16x8 B1 = *(const bf16x8*)(bf_lane + ((size_t)(fr + 4 + g) << 9));  // h=1
      acc[0][g] = __builtin_amdgcn_mfma_f32_16x16x32_bf16(A0_0, B0, acc[0][g], 0, 0, 0);
      acc[0][g] = __builtin_amdgcn_mfma_f32_16x16x32_bf16(A0_1, B1, acc[0][g], 0, 0, 0);
      acc[1][g] = __builtin_amdgcn_mfma_f32_16x16x32_bf16(A1_0, B0, acc[1][g], 0, 0, 0);
      acc[1][g] = __builtin_amdgcn_mfma_f32_16x16x32_bf16(A1_1, B1, acc[1][g], 0, 0, 0);
      acc[2][g] = __builtin_amdgcn_mfma_f32_16x16x32_bf16(A2_0, B0, acc[2][g], 0, 0, 0);
      acc[2][g] = __builtin_amdgcn_mfma_f32_16x16x32_bf16(A2_1, B1, acc[2][g], 0, 0, 0);
      acc[3][g] = __builtin_amdgcn_mfma_f32_16x16x32_bf16(A3_0, B0, acc[3][g], 0, 0, 0);
      acc[3][g] = __builtin_amdgcn_mfma_f32_16x16x32_bf16(A3_1, B1, acc[3][g], 0, 0, 0);
    }
  }

  // chunked LDS reduction across the 8 waves (one row-group at a time)
  #pragma unroll
  for (int rg = 0; rg < 4; rg++){
    if (wave > 0){
      #pragma unroll
      for (int g = 0; g < 4; g++)
        #pragma unroll
        for (int q = 0; q < 4; q++)
          red[wave - 1][lane][g * 4 + q] = acc[rg][g][q];
    }
    __syncthreads();
    if (wave == 0){
      #pragma unroll
      for (int w = 0; w < 7; w++)
        #pragma unroll
        for (int g = 0; g < 4; g++)
          #pragma unroll
          for (int q = 0; q < 4; q++)
            acc[rg][g][q] += red[w][lane][g * 4 + q];
    }
    __syncthreads();
  }

  // wave0-only atomic epilogue: one add per output per half-block
  // C/D layout: col = lane&15, row = (lane>>4)*4 + q (m89-verified)
  if (wave == 0){
    int q4 = (lane >> 4) * 4, col = lane & 15;
    #pragma unroll
    for (int rg = 0; rg < 4; rg++){
      #pragma unroll
      for (int q = 0; q < 4; q++){
        int m = m0 + rg * 16 + q4 + q;
        float* orow = out_lat + (((size_t)(b * M0 + m)) << 6);
        #pragma unroll
        for (int g = 0; g < 4; g++){
          atomicAdd(&orow[g * 16 + col], acc[rg][g][q]);
        }
      }
    }
  }
}

// ============ slice + bias + transpose to [b][o][n], 16-row tiles =========
__global__ void k_slice(const float* __restrict__ bary_pv, const int* __restrict__ idx_pv,
                        const float* __restrict__ out_lat, const float* __restrict__ bias,
                        const float* __restrict__ bmul, float* __restrict__ out){
  __shared__ float tile[16][65];
  int b = blockIdx.x >> 6, n0 = (blockIdx.x & 63) * 16;
  int tid = threadIdx.x;
  int wave = tid >> 6, o = tid & 63;
  float bo = bias[o];
  #pragma unroll
  for (int i = 0; i < 4; i++){
    int n = wave * 4 + i;
    int p = (b << 10) + n0 + n;
    float acc = bo * bmul[n0 + n];
    int base = p * NVERT;
    #pragma unroll
    for (int kk = 0; kk < NVERT; kk++){
      int u = idx_pv[base + kk];
      acc += bary_pv[base + kk] * out_lat[(((size_t)(b * M0 + u)) << 6) + o];
    }
    tile[n][o] = acc;
  }
  __syncthreads();
  int nl = tid & 15;
  #pragma unroll
  for (int i = 0; i < 4; i++){
    int o2 = (tid >> 4) + i * 16;
    out[(((size_t)b * 64 + o2) << 10) + n0 + nl] = tile[nl][o2];
  }
}

extern "C" void kernel_launch(void* const* d_in, const int* in_sizes, int n_in,
                              void* d_out, int out_size, void* d_ws, size_t ws_size,
                              hipStream_t stream){
  const float* data = (const float*)d_in[0];
  const float* feat = (const float*)d_in[1];
  const float* wk   = (const float*)d_in[2];
  const float* bias = (const float*)d_in[3];
  const float* bmul = (const float*)d_in[4];
  float* out = (float*)d_out;

  char* ws = (char*)d_ws;
  size_t off = 0;
  auto alloc = [&](size_t bytes){
    void* p = ws + off;
    off = (off + bytes + 255) & ~(size_t)255;
    return p;
  };
  int*   codes_pv = (int*)  alloc((size_t)BATCH * M0 * 4);
  float* bary_pv  = (float*)alloc((size_t)BATCH * M0 * 4);
  int*   idx_pv   = (int*)  alloc((size_t)BATCH * M0 * 4);
  int*   hash_code= (int*)  alloc((size_t)BATCH * CAP * 4);
  int*   hash_uid = (int*)  alloc((size_t)BATCH * CAP * 4);
  int*   ucount   = (int*)  alloc(256);
  int*   ukeys    = (int*)  alloc((size_t)BATCH * M0 * DD * 4);
  float* table    = (float*)alloc((size_t)BATCH * M0 * CIN * 4);
  float* out_lat  = (float*)alloc((size_t)BATCH * M0 * COUT * 4);
  unsigned short* bpf      = (unsigned short*)alloc((size_t)COUT * KTOT * 2);
  unsigned short* table_bf = (unsigned short*)alloc(((size_t)BATCH * M0 + 8) * CIN * 2);
  float* dat_t    = (float*)alloc((size_t)BATCH * NPTS * CIN * 4);
  int*   nuid     = (int*)  alloc((size_t)BATCH * M0 * 32 * 4);

  k_a     <<<1024, 256, 0, stream>>>(wk, data, feat, hash_code, hash_uid, ucount,
                                     (float4*)table, (float4*)out_lat, bpf, dat_t,
                                     codes_pv, bary_pv);
  k_insert<<<BATCH * M0 / 256, 256, 0, stream>>>(codes_pv, hash_code, hash_uid, ucount, ukeys);
  k_sn    <<<BATCH * NPTS / 4 + BATCH * M0 * 32 / 256, 256, 0, stream>>>(
            dat_t, codes_pv, bary_pv, hash_code, hash_uid, ucount, ukeys,
            idx_pv, table, nuid);
  k_tobf  <<<BATCH * M0 * CIN / 8 / 256, 256, 0, stream>>>(table, ucount, table_bf);
  k_conv  <<<BATCH * 160, 512, 0, stream>>>(ucount, nuid, table_bf, bpf, out_lat);
  k_slice <<<BATCH * 64, 256, 0, stream>>>(bary_pv, idx_pv, out_lat, bias, bmul, out);
}